// Round 2
// 238.469 us; speedup vs baseline: 1.0244x; 1.0244x over previous
//
#include <hip/hip_runtime.h>
#include <math.h>

// CSR segmented softmax, round 4 (resubmit — round-1 bench hit a GPU
// acquisition timeout, no data): drop nbuf/rpn, in-place LDS scale,
// wave-uniform group guards.
//   - one 64-lane wave per block owns 64 consecutive nodes (contiguous edges)
//   - range/wstart hoisted to SGPR via readfirstlane/readlane -> scalar
//     branches skip whole groups beyond range (avg range 1024 of CAP 2048,
//     so ~half the exp/max/store work disappears; no memory ops were in the
//     skipped groups, so load MLP is unchanged)
//   - phase 1: strided global->reg load, wave max, exp in regs, ds_write_b128
//   - phase 2: lane-per-node sum from LDS (float4 reads, ~deg/4 iters)
//   - phase 3: lane scales ITS OWN segment in LDS by 1/s (float4 RMW) --
//     replaces the old nbuf-write loop at the same divergent-iteration cost
//     and kills phase 4's id-unpack + ragged rpn gathers entirely
//   - phase 4: conflict-free strided b128 read -> coalesced global store
// LDS 8 KB/block -> 20 blocks/CU (was 10.5 KB -> 15).
#define NPW 64
#define BLOCK 64
#define CAP 2048          // max edges per wave (proven: never exceeded; 8 sigma)
#define MAXG (CAP / 256)  // 8 groups of 4 floats per lane

struct __align__(16) WaveLds {
  float ebuf[CAP];   // exp values, then scaled in place
};

__global__ __launch_bounds__(BLOCK, 4)
void seg_softmax_kernel(const int* __restrict__ row_ptr,
                        const float* __restrict__ scores,
                        float* __restrict__ out, int n_nodes) {
  __shared__ WaveLds L;      // 8192 B
  const int lane = threadIdx.x;
  const int base = blockIdx.x * NPW;
  const int i0 = min(base + lane, n_nodes);
  const int i1 = min(base + lane + 1, n_nodes);
  const int ls = row_ptr[i0];
  const int le = row_ptr[i1];
  // wave-uniform scalars -> SGPR: scalar branches + s+v addressing
  const int wstart = __builtin_amdgcn_readfirstlane(ls);
  const int wend   = __builtin_amdgcn_readlane(le, 63);
  const int range  = wend - wstart;

  if (range <= CAP) {
    const int a = ls - wstart, b = le - wstart;

    // ---- phase 1: global -> regs (strided, coalesced), wave max, exp, -> LDS
    // dead groups (256g >= range) are skipped by scalar branch and their v[]
    // stay uninitialized -- every later use is guarded by the same condition.
    float v[4 * MAXG];
    #pragma unroll
    for (int g = 0; g < MAXG; ++g) {
      if (256 * g < range) {                       // wave-uniform (SGPR)
        const int j0 = 4 * lane + 256 * g;
        if (j0 + 4 <= range) {
          #pragma unroll
          for (int k = 0; k < 4; ++k) v[4 * g + k] = scores[wstart + j0 + k];
        } else {
          #pragma unroll
          for (int k = 0; k < 4; ++k)
            v[4 * g + k] = (j0 + k < range) ? scores[wstart + j0 + k] : -INFINITY;
        }
      }
    }
    float m = -INFINITY;
    #pragma unroll
    for (int g = 0; g < MAXG; ++g) {
      if (256 * g < range) {
        #pragma unroll
        for (int k = 0; k < 4; ++k) m = fmaxf(m, v[4 * g + k]);
      }
    }
    #pragma unroll
    for (int off = 32; off >= 1; off >>= 1) m = fmaxf(m, __shfl_xor(m, off));
    // range>0 -> m finite; exp(-inf - m) = 0 for padding lanes.
    #pragma unroll
    for (int g = 0; g < MAXG; ++g) {
      if (256 * g < range) {
        #pragma unroll
        for (int k = 0; k < 4; ++k) v[4 * g + k] = __expf(v[4 * g + k] - m);
      }
    }
    #pragma unroll
    for (int g = 0; g < MAXG; ++g) {
      if (256 * g < range) {
        const int j0 = 4 * lane + 256 * g;
        if (j0 + 4 <= range) {
          float4 q = make_float4(v[4 * g], v[4 * g + 1], v[4 * g + 2], v[4 * g + 3]);
          *(float4*)&L.ebuf[j0] = q;               // 16B-aligned -> ds_write_b128
        } else if (j0 < range) {
          #pragma unroll
          for (int k = 0; k < 4; ++k)
            if (j0 + k < range) L.ebuf[j0 + k] = v[4 * g + k];
        }
      }
    }
    __syncthreads();

    // ---- phase 2: per-node sum (own segment, float4 reads, no loaded-branch)
    float s = 0.0f;
    {
      int j = a;
      while (j < b && (j & 3)) { s += L.ebuf[j]; ++j; }   // head to 16B align
      float s1 = 0.0f, s2 = 0.0f, s3 = 0.0f;
      for (; j + 4 <= b; j += 4) {
        const float4 q = *(const float4*)&L.ebuf[j];      // ds_read_b128
        s += q.x; s1 += q.y; s2 += q.z; s3 += q.w;
      }
      for (; j < b; ++j) s += L.ebuf[j];                  // tail
      s += (s1 + s2) + s3;
    }
    const float r = 1.0f / s;   // empty node -> inf, writes nothing below

    // ---- phase 3: scale OWN segment in place (disjoint segments, no hazard;
    //       same wave, exec-masked loops -- no barrier needed vs phase 2)
    {
      int j = a;
      while (j < b && (j & 3)) { L.ebuf[j] *= r; ++j; }
      for (; j + 4 <= b; j += 4) {
        float4 q = *(float4*)&L.ebuf[j];
        q.x *= r; q.y *= r; q.z *= r; q.w *= r;
        *(float4*)&L.ebuf[j] = q;
      }
      for (; j < b; ++j) L.ebuf[j] *= r;
    }
    __syncthreads();

    // ---- phase 4: strided, conflict-free b128 read -> coalesced store
    #pragma unroll
    for (int g = 0; g < MAXG; ++g) {
      if (256 * g < range) {
        const int j0 = 4 * lane + 256 * g;
        if (j0 + 4 <= range) {
          const float4 q = *(const float4*)&L.ebuf[j0];
          out[wstart + j0 + 0] = q.x;
          out[wstart + j0 + 1] = q.y;
          out[wstart + j0 + 2] = q.z;
          out[wstart + j0 + 3] = q.w;
        } else if (j0 < range) {
          #pragma unroll
          for (int k = 0; k < 4; ++k)
            if (j0 + k < range) out[wstart + j0 + k] = L.ebuf[j0 + k];
        }
      }
    }
  } else {
    // fallback (range > CAP): direct-global, never taken on this data.
    // Single-wave block + wave-uniform branch -> no barrier-matching hazard.
    float m = -INFINITY;
    for (int j = ls; j < le; ++j) m = fmaxf(m, scores[j]);
    float s = 0.0f;
    for (int j = ls; j < le; ++j) {
      const float e = __expf(scores[j] - m);
      s += e;
      out[j] = e;
    }
    const float r = 1.0f / s;
    for (int j = ls; j < le; ++j) out[j] *= r;
  }
}

extern "C" void kernel_launch(void* const* d_in, const int* in_sizes, int n_in,
                              void* d_out, int out_size, void* d_ws, size_t ws_size,
                              hipStream_t stream) {
  const int*   row_ptr = (const int*)d_in[0];
  const float* scores  = (const float*)d_in[1];
  float*       out     = (float*)d_out;
  const int n_nodes = in_sizes[0] - 1;
  const int blocks  = (n_nodes + NPW - 1) / NPW;
  seg_softmax_kernel<<<blocks, BLOCK, 0, stream>>>(row_ptr, scores, out, n_nodes);
}